// Round 1
// baseline (1921.838 us; speedup 1.0000x reference)
//
#include <hip/hip_runtime.h>
#include <hip/hip_bf16.h>
#include <math.h>

#define HIDDEN 1024
#define NEXP 8
#define TOPK 2
#define INTER 1408
#define SINTER 2816
#define NTOK 4096
#define NROWS (NTOK * TOPK) /* 8192 */

#define BM 64
#define BN 64
#define BK 16

__device__ __forceinline__ float silu_f(float g) {
    return g * (1.0f / (1.0f + __expf(-g)));
}

// ---------------- gate: logits -> softmax -> top2 -> normalized weights ----
__global__ void gate_kernel(const float* __restrict__ x, const float* __restrict__ gw,
                            int* __restrict__ top_i, float* __restrict__ top_w) {
    int t = blockIdx.x;
    int lane = threadIdx.x;
    const float* xr = x + (size_t)t * HIDDEN;
    float acc[NEXP];
#pragma unroll
    for (int e = 0; e < NEXP; e++) acc[e] = 0.f;
    for (int j = 0; j < HIDDEN / 64; j++) {
        float xv = xr[lane + 64 * j];
#pragma unroll
        for (int e = 0; e < NEXP; e++)
            acc[e] = fmaf(xv, gw[e * HIDDEN + lane + 64 * j], acc[e]);
    }
#pragma unroll
    for (int e = 0; e < NEXP; e++) {
        float v = acc[e];
        for (int off = 32; off > 0; off >>= 1) v += __shfl_xor(v, off, 64);
        acc[e] = v;
    }
    if (lane == 0) {
        float mx = acc[0];
        for (int e = 1; e < NEXP; e++) mx = fmaxf(mx, acc[e]);
        float s[NEXP];
        float sum = 0.f;
        for (int e = 0; e < NEXP; e++) { s[e] = __expf(acc[e] - mx); sum += s[e]; }
        float inv = 1.0f / sum;
        for (int e = 0; e < NEXP; e++) s[e] *= inv;
        int e0 = 0;
        for (int e = 1; e < NEXP; e++) if (s[e] > s[e0]) e0 = e;
        int e1 = -1;
        for (int e = 0; e < NEXP; e++) {
            if (e == e0) continue;
            if (e1 < 0 || s[e] > s[e1]) e1 = e;
        }
        float w0 = s[e0], w1 = s[e1];
        float denom = w0 + w1 + 1e-20f;
        top_i[t * 2 + 0] = e0;
        top_i[t * 2 + 1] = e1;
        top_w[t * 2 + 0] = w0 / denom;
        top_w[t * 2 + 1] = w1 / denom;
    }
}

// ---------------- routing bookkeeping ----------------
__global__ void assign_kernel(const int* __restrict__ top_i, int* __restrict__ cnt,
                              int* __restrict__ rnk) {
    int j = blockIdx.x * blockDim.x + threadIdx.x;
    if (j < NROWS) rnk[j] = atomicAdd(&cnt[top_i[j]], 1);
}

__global__ void scan_kernel(const int* __restrict__ cnt, int* __restrict__ offs) {
    if (threadIdx.x == 0) {
        int o = 0;
        for (int e = 0; e < NEXP; e++) { offs[e] = o; o += cnt[e]; }
        offs[NEXP] = o;
    }
}

__global__ void fill_kernel(const int* __restrict__ top_i, const float* __restrict__ top_w,
                            const int* __restrict__ rnk, const int* __restrict__ offs,
                            int* __restrict__ tok_of_row, float* __restrict__ w_of_row) {
    int j = blockIdx.x * blockDim.x + threadIdx.x;
    if (j < NROWS) {
        int row = offs[top_i[j]] + rnk[j];
        tok_of_row[row] = j;  // encodes token (j>>1) and k (j&1)
        w_of_row[row] = top_w[j];
    }
}

// ---------------- shared expert GEMM1: act = silu(x@swg) * (x@swu) ---------
__global__ __launch_bounds__(256) void sgemm_gu(const float* __restrict__ A,
                                                const float* __restrict__ Bg,
                                                const float* __restrict__ Bu,
                                                float* __restrict__ actout,
                                                int M, int N, int K) {
    __shared__ float As[BK][BM];
    __shared__ float Bsg[BK][BN];
    __shared__ float Bsu[BK][BN];
    int m0 = blockIdx.y * BM, n0 = blockIdx.x * BN;
    int tid = threadIdx.x;
    int tx = tid & 15, ty = tid >> 4;
    float accG[4][4] = {};
    float accU[4][4] = {};
    int arow = tid >> 2, akq = (tid & 3) * 4;
    int brow = tid >> 4, bnq = (tid & 15) * 4;
    for (int k0 = 0; k0 < K; k0 += BK) {
        float4 av = *reinterpret_cast<const float4*>(&A[(size_t)(m0 + arow) * K + k0 + akq]);
        As[akq + 0][arow] = av.x; As[akq + 1][arow] = av.y;
        As[akq + 2][arow] = av.z; As[akq + 3][arow] = av.w;
        *reinterpret_cast<float4*>(&Bsg[brow][bnq]) =
            *reinterpret_cast<const float4*>(&Bg[(size_t)(k0 + brow) * N + n0 + bnq]);
        *reinterpret_cast<float4*>(&Bsu[brow][bnq]) =
            *reinterpret_cast<const float4*>(&Bu[(size_t)(k0 + brow) * N + n0 + bnq]);
        __syncthreads();
#pragma unroll
        for (int k = 0; k < BK; k++) {
            float a[4], bg[4], bu[4];
            *reinterpret_cast<float4*>(a) = *reinterpret_cast<const float4*>(&As[k][ty * 4]);
            *reinterpret_cast<float4*>(bg) = *reinterpret_cast<const float4*>(&Bsg[k][tx * 4]);
            *reinterpret_cast<float4*>(bu) = *reinterpret_cast<const float4*>(&Bsu[k][tx * 4]);
#pragma unroll
            for (int im = 0; im < 4; im++)
#pragma unroll
                for (int in = 0; in < 4; in++) {
                    accG[im][in] = fmaf(a[im], bg[in], accG[im][in]);
                    accU[im][in] = fmaf(a[im], bu[in], accU[im][in]);
                }
        }
        __syncthreads();
    }
#pragma unroll
    for (int im = 0; im < 4; im++)
#pragma unroll
        for (int in = 0; in < 4; in++) {
            float g = accG[im][in], u = accU[im][in];
            actout[(size_t)(m0 + ty * 4 + im) * N + n0 + tx * 4 + in] = silu_f(g) * u;
        }
}

// ---------------- shared expert GEMM2: out = act @ swd (plain store) -------
__global__ __launch_bounds__(256) void sgemm_down(const float* __restrict__ A,
                                                  const float* __restrict__ B,
                                                  float* __restrict__ out,
                                                  int M, int N, int K) {
    __shared__ float As[BK][BM];
    __shared__ float Bs[BK][BN];
    int m0 = blockIdx.y * BM, n0 = blockIdx.x * BN;
    int tid = threadIdx.x;
    int tx = tid & 15, ty = tid >> 4;
    float acc[4][4] = {};
    int arow = tid >> 2, akq = (tid & 3) * 4;
    int brow = tid >> 4, bnq = (tid & 15) * 4;
    for (int k0 = 0; k0 < K; k0 += BK) {
        float4 av = *reinterpret_cast<const float4*>(&A[(size_t)(m0 + arow) * K + k0 + akq]);
        As[akq + 0][arow] = av.x; As[akq + 1][arow] = av.y;
        As[akq + 2][arow] = av.z; As[akq + 3][arow] = av.w;
        *reinterpret_cast<float4*>(&Bs[brow][bnq]) =
            *reinterpret_cast<const float4*>(&B[(size_t)(k0 + brow) * N + n0 + bnq]);
        __syncthreads();
#pragma unroll
        for (int k = 0; k < BK; k++) {
            float a[4], b[4];
            *reinterpret_cast<float4*>(a) = *reinterpret_cast<const float4*>(&As[k][ty * 4]);
            *reinterpret_cast<float4*>(b) = *reinterpret_cast<const float4*>(&Bs[k][tx * 4]);
#pragma unroll
            for (int im = 0; im < 4; im++)
#pragma unroll
                for (int in = 0; in < 4; in++)
                    acc[im][in] = fmaf(a[im], b[in], acc[im][in]);
        }
        __syncthreads();
    }
#pragma unroll
    for (int im = 0; im < 4; im++)
#pragma unroll
        for (int in = 0; in < 4; in++)
            out[(size_t)(m0 + ty * 4 + im) * N + n0 + tx * 4 + in] = acc[im][in];
}

// ---------------- routed GEMM1 (gather rows of x, per-expert weights) ------
__global__ __launch_bounds__(256) void rgemm_gu(const float* __restrict__ x,
                                                const float* __restrict__ Wg,
                                                const float* __restrict__ Wu,
                                                float* __restrict__ act,
                                                const int* __restrict__ tok_of_row,
                                                const int* __restrict__ offs,
                                                const int* __restrict__ cnt) {
    int e = blockIdx.z;
    int mcnt = cnt[e];
    int m0 = blockIdx.y * BM;
    if (m0 >= mcnt) return;
    int base = offs[e];
    int n0 = blockIdx.x * BN;
    const float* Bg = Wg + (size_t)e * HIDDEN * INTER;
    const float* Bu = Wu + (size_t)e * HIDDEN * INTER;
    __shared__ float As[BK][BM];
    __shared__ float Bsg[BK][BN];
    __shared__ float Bsu[BK][BN];
    int tid = threadIdx.x;
    int tx = tid & 15, ty = tid >> 4;
    float accG[4][4] = {};
    float accU[4][4] = {};
    int arow = tid >> 2, akq = (tid & 3) * 4;
    int brow = tid >> 4, bnq = (tid & 15) * 4;
    bool avalid = (m0 + arow) < mcnt;
    int tok = avalid ? (tok_of_row[base + m0 + arow] >> 1) : 0;
    for (int k0 = 0; k0 < HIDDEN; k0 += BK) {
        float4 av = make_float4(0.f, 0.f, 0.f, 0.f);
        if (avalid)
            av = *reinterpret_cast<const float4*>(&x[(size_t)tok * HIDDEN + k0 + akq]);
        As[akq + 0][arow] = av.x; As[akq + 1][arow] = av.y;
        As[akq + 2][arow] = av.z; As[akq + 3][arow] = av.w;
        *reinterpret_cast<float4*>(&Bsg[brow][bnq]) =
            *reinterpret_cast<const float4*>(&Bg[(size_t)(k0 + brow) * INTER + n0 + bnq]);
        *reinterpret_cast<float4*>(&Bsu[brow][bnq]) =
            *reinterpret_cast<const float4*>(&Bu[(size_t)(k0 + brow) * INTER + n0 + bnq]);
        __syncthreads();
#pragma unroll
        for (int k = 0; k < BK; k++) {
            float a[4], bg[4], bu[4];
            *reinterpret_cast<float4*>(a) = *reinterpret_cast<const float4*>(&As[k][ty * 4]);
            *reinterpret_cast<float4*>(bg) = *reinterpret_cast<const float4*>(&Bsg[k][tx * 4]);
            *reinterpret_cast<float4*>(bu) = *reinterpret_cast<const float4*>(&Bsu[k][tx * 4]);
#pragma unroll
            for (int im = 0; im < 4; im++)
#pragma unroll
                for (int in = 0; in < 4; in++) {
                    accG[im][in] = fmaf(a[im], bg[in], accG[im][in]);
                    accU[im][in] = fmaf(a[im], bu[in], accU[im][in]);
                }
        }
        __syncthreads();
    }
#pragma unroll
    for (int im = 0; im < 4; im++) {
        int gm = m0 + ty * 4 + im;
        if (gm < mcnt) {
#pragma unroll
            for (int in = 0; in < 4; in++) {
                float g = accG[im][in], u = accU[im][in];
                act[(size_t)(base + gm) * INTER + n0 + tx * 4 + in] = silu_f(g) * u;
            }
        }
    }
}

// ---------------- routed GEMM2: out += w * (act @ wd[e]) (atomic) ----------
__global__ __launch_bounds__(256) void rgemm_down(const float* __restrict__ act,
                                                  const float* __restrict__ Wd,
                                                  float* __restrict__ out,
                                                  const int* __restrict__ tok_of_row,
                                                  const float* __restrict__ w_of_row,
                                                  const int* __restrict__ offs,
                                                  const int* __restrict__ cnt) {
    int e = blockIdx.z;
    int mcnt = cnt[e];
    int m0 = blockIdx.y * BM;
    if (m0 >= mcnt) return;
    int base = offs[e];
    int n0 = blockIdx.x * BN;
    const float* B = Wd + (size_t)e * INTER * HIDDEN;
    __shared__ float As[BK][BM];
    __shared__ float Bs[BK][BN];
    int tid = threadIdx.x;
    int tx = tid & 15, ty = tid >> 4;
    float acc[4][4] = {};
    int arow = tid >> 2, akq = (tid & 3) * 4;
    int brow = tid >> 4, bnq = (tid & 15) * 4;
    bool avalid = (m0 + arow) < mcnt;
    for (int k0 = 0; k0 < INTER; k0 += BK) {
        float4 av = make_float4(0.f, 0.f, 0.f, 0.f);
        if (avalid)
            av = *reinterpret_cast<const float4*>(&act[(size_t)(base + m0 + arow) * INTER + k0 + akq]);
        As[akq + 0][arow] = av.x; As[akq + 1][arow] = av.y;
        As[akq + 2][arow] = av.z; As[akq + 3][arow] = av.w;
        *reinterpret_cast<float4*>(&Bs[brow][bnq]) =
            *reinterpret_cast<const float4*>(&B[(size_t)(k0 + brow) * HIDDEN + n0 + bnq]);
        __syncthreads();
#pragma unroll
        for (int k = 0; k < BK; k++) {
            float a[4], b[4];
            *reinterpret_cast<float4*>(a) = *reinterpret_cast<const float4*>(&As[k][ty * 4]);
            *reinterpret_cast<float4*>(b) = *reinterpret_cast<const float4*>(&Bs[k][tx * 4]);
#pragma unroll
            for (int im = 0; im < 4; im++)
#pragma unroll
                for (int in = 0; in < 4; in++)
                    acc[im][in] = fmaf(a[im], b[in], acc[im][in]);
        }
        __syncthreads();
    }
#pragma unroll
    for (int im = 0; im < 4; im++) {
        int gm = m0 + ty * 4 + im;
        if (gm < mcnt) {
            int tok = tok_of_row[base + gm] >> 1;
            float w = w_of_row[base + gm];
#pragma unroll
            for (int in = 0; in < 4; in++)
                atomicAdd(&out[(size_t)tok * HIDDEN + n0 + tx * 4 + in], w * acc[im][in]);
        }
    }
}

extern "C" void kernel_launch(void* const* d_in, const int* in_sizes, int n_in,
                              void* d_out, int out_size, void* d_ws, size_t ws_size,
                              hipStream_t stream) {
    const float* x   = (const float*)d_in[0];
    const float* gw  = (const float*)d_in[1];
    const float* wg  = (const float*)d_in[2];
    const float* wu  = (const float*)d_in[3];
    const float* wd  = (const float*)d_in[4];
    const float* swg = (const float*)d_in[5];
    const float* swu = (const float*)d_in[6];
    const float* swd = (const float*)d_in[7];
    float* out = (float*)d_out;

    // workspace layout
    const size_t ACT_ELEMS = (size_t)NROWS * INTER;  // == NTOK * SINTER == 11,534,336
    float* act = (float*)d_ws;
    int* ib = (int*)(act + ACT_ELEMS);
    int* top_i = ib;                    // NROWS
    int* rnk = ib + NROWS;              // NROWS
    int* cnt = ib + 2 * NROWS;          // NEXP
    int* offs = ib + 2 * NROWS + NEXP;  // NEXP+1
    int* tok_of_row = ib + 2 * NROWS + 2 * NEXP + 1;  // NROWS
    float* top_w = (float*)(ib + 3 * NROWS + 2 * NEXP + 1);  // NROWS
    float* w_of_row = top_w + NROWS;                          // NROWS

    // 1. gate + routing bookkeeping
    gate_kernel<<<NTOK, 64, 0, stream>>>(x, gw, top_i, top_w);
    hipMemsetAsync(cnt, 0, NEXP * sizeof(int), stream);
    assign_kernel<<<NROWS / 256, 256, 0, stream>>>(top_i, cnt, rnk);
    scan_kernel<<<1, 1, 0, stream>>>(cnt, offs);
    fill_kernel<<<NROWS / 256, 256, 0, stream>>>(top_i, top_w, rnk, offs, tok_of_row, w_of_row);

    // 2. shared expert (writes out densely)
    sgemm_gu<<<dim3(SINTER / BN, NTOK / BM), 256, 0, stream>>>(x, swg, swu, act,
                                                               NTOK, SINTER, HIDDEN);
    sgemm_down<<<dim3(HIDDEN / BN, NTOK / BM), 256, 0, stream>>>(act, swd, out,
                                                                 NTOK, HIDDEN, SINTER);

    // 3. routed experts (atomic accumulate on top of shared output)
    rgemm_gu<<<dim3(INTER / BN, NTOK / BM, NEXP), 256, 0, stream>>>(x, wg, wu, act,
                                                                    tok_of_row, offs, cnt);
    rgemm_down<<<dim3(HIDDEN / BN, NTOK / BM, NEXP), 256, 0, stream>>>(act, wd, out,
                                                                       tok_of_row, w_of_row,
                                                                       offs, cnt);
}

// Round 2
// 389.764 us; speedup vs baseline: 4.9308x; 4.9308x over previous
//
#include <hip/hip_runtime.h>
#include <hip/hip_bf16.h>
#include <math.h>

#define HIDDEN 1024
#define NEXP 8
#define TOPK 2
#define INTER 1408
#define SINTER 2816
#define NTOK 4096
#define NROWS (NTOK * TOPK) /* 8192 routed rows */
#define NPANEL 10           /* 8 routed + 2 shared halves */
#define TROWS 16384         /* NROWS + 2*NTOK */

typedef unsigned short ushort_t;
typedef __attribute__((ext_vector_type(8))) short short8;
typedef __attribute__((ext_vector_type(4))) float f32x4;

__device__ __forceinline__ ushort_t f2bf(float f) {
    unsigned int b = __float_as_uint(f);
    unsigned int r = (b + 0x7FFFu + ((b >> 16) & 1u)) >> 16;
    return (ushort_t)r;
}
__device__ __forceinline__ float silu_f(float g) {
    return g * (1.0f / (1.0f + __expf(-g)));
}

#define GLDS16(gp, lp) __builtin_amdgcn_global_load_lds(                     \
    (const __attribute__((address_space(1))) void*)(gp),                     \
    (__attribute__((address_space(3))) void*)(lp), 16, 0, 0)

// ---------------- fp32 -> bf16 elementwise (x) ----------------
__global__ void conv_x(const float* __restrict__ src, ushort_t* __restrict__ dst) {
    int i = (blockIdx.x * 256 + threadIdx.x) * 4;
    float4 v = *reinterpret_cast<const float4*>(&src[i]);
    union { ushort_t h[4]; unsigned long long ll; } p;
    p.h[0] = f2bf(v.x); p.h[1] = f2bf(v.y); p.h[2] = f2bf(v.z); p.h[3] = f2bf(v.w);
    *reinterpret_cast<unsigned long long*>(&dst[i]) = p.ll;
}

// ---------------- fp32 [R][C] -> bf16 [C][R] transpose-convert -------------
__global__ void tconv(const float* __restrict__ src, ushort_t* __restrict__ dst,
                      int R, int C, long sstride, long dstride) {
    src += (size_t)blockIdx.z * sstride;
    dst += (size_t)blockIdx.z * dstride;
    __shared__ float tile[32][33];
    int ct = blockIdx.x * 32, rt = blockIdx.y * 32;
    int tx = threadIdx.x, ty = threadIdx.y;  // 32 x 8
#pragma unroll
    for (int i = 0; i < 4; i++)
        tile[ty + 8 * i][tx] = src[(size_t)(rt + ty + 8 * i) * C + ct + tx];
    __syncthreads();
#pragma unroll
    for (int i = 0; i < 4; i++)
        dst[(size_t)(ct + ty + 8 * i) * R + rt + tx] = f2bf(tile[tx][ty + 8 * i]);
}

// ---------------- gate: logits -> softmax -> top2 -> normalized weights ----
__global__ void gate_kernel(const float* __restrict__ x, const float* __restrict__ gw,
                            int* __restrict__ top_i, float* __restrict__ top_w) {
    int t = blockIdx.x;
    int lane = threadIdx.x;
    const float* xr = x + (size_t)t * HIDDEN;
    float acc[NEXP];
#pragma unroll
    for (int e = 0; e < NEXP; e++) acc[e] = 0.f;
    for (int j = 0; j < HIDDEN / 64; j++) {
        float xv = xr[lane + 64 * j];
#pragma unroll
        for (int e = 0; e < NEXP; e++)
            acc[e] = fmaf(xv, gw[e * HIDDEN + lane + 64 * j], acc[e]);
    }
#pragma unroll
    for (int e = 0; e < NEXP; e++) {
        float v = acc[e];
        for (int off = 32; off > 0; off >>= 1) v += __shfl_xor(v, off, 64);
        acc[e] = v;
    }
    if (lane == 0) {
        float mx = acc[0];
        for (int e = 1; e < NEXP; e++) mx = fmaxf(mx, acc[e]);
        float s[NEXP];
        float sum = 0.f;
        for (int e = 0; e < NEXP; e++) { s[e] = __expf(acc[e] - mx); sum += s[e]; }
        float inv = 1.0f / sum;
        for (int e = 0; e < NEXP; e++) s[e] *= inv;
        int e0 = 0;
        for (int e = 1; e < NEXP; e++) if (s[e] > s[e0]) e0 = e;
        int e1 = -1;
        for (int e = 0; e < NEXP; e++) {
            if (e == e0) continue;
            if (e1 < 0 || s[e] > s[e1]) e1 = e;
        }
        float w0 = s[e0], w1 = s[e1];
        float denom = w0 + w1 + 1e-20f;
        top_i[t * 2 + 0] = e0;
        top_i[t * 2 + 1] = e1;
        top_w[t * 2 + 0] = w0 / denom;
        top_w[t * 2 + 1] = w1 / denom;
    }
}

// ---------------- routing bookkeeping ----------------
__global__ void assign_kernel(const int* __restrict__ top_i, int* __restrict__ cnt,
                              int* __restrict__ rnk) {
    int j = blockIdx.x * blockDim.x + threadIdx.x;
    if (j < NROWS) rnk[j] = atomicAdd(&cnt[top_i[j]], 1);
}

__global__ void scan_kernel(const int* __restrict__ cnt, int* __restrict__ offs2,
                            int* __restrict__ cnt2) {
    if (threadIdx.x == 0) {
        int o = 0;
        for (int e = 0; e < NEXP; e++) { offs2[e] = o; cnt2[e] = cnt[e]; o += cnt[e]; }
        offs2[8] = NROWS;          cnt2[8] = NTOK;
        offs2[9] = NROWS + NTOK;   cnt2[9] = NTOK;
        offs2[10] = TROWS;
    }
}

__global__ void fill_kernel(const int* __restrict__ top_i, const float* __restrict__ top_w,
                            const int* __restrict__ rnk, const int* __restrict__ offs2,
                            int* __restrict__ tok_of_row, float* __restrict__ w_of_row) {
    int j = blockIdx.x * blockDim.x + threadIdx.x;
    if (j < NROWS) {
        int row = offs2[top_i[j]] + rnk[j];
        tok_of_row[row] = j;  // token = j>>1
        w_of_row[row] = top_w[j];
    }
}

__global__ void fill_shared(int* __restrict__ tok_of_row, float* __restrict__ w_of_row) {
    int j = blockIdx.x * blockDim.x + threadIdx.x;  // 0..8191
    int row = NROWS + j;
    tok_of_row[row] = (j & (NTOK - 1)) << 1;  // token = j mod 4096
    w_of_row[row] = 1.0f;
}

// ---------------- MFMA grouped GEMM 1: act = silu(x@Wg)*(x@Wu) -------------
// A: xb [NTOK][HIDDEN] bf16 gathered by tok_of_row; B: WgT/WuT [panel][INTER][HIDDEN]
// Tile 128x128, BK=32, 4 waves (each 64x64 = 4x4 frags of 16x16x32).
__global__ __launch_bounds__(256, 2) void gemm_gu(
    const ushort_t* __restrict__ xb, const ushort_t* __restrict__ WgT,
    const ushort_t* __restrict__ WuT, ushort_t* __restrict__ act,
    const int* __restrict__ tok_of_row, const int* __restrict__ offs2,
    const int* __restrict__ cnt2) {
    int e = blockIdx.z;
    int mcnt = cnt2[e];
    int m0 = blockIdx.y * 128;
    if (m0 >= mcnt) return;
    int base = offs2[e];
    int n0 = blockIdx.x * 128;
    const ushort_t* Bg = WgT + (size_t)e * INTER * HIDDEN;
    const ushort_t* Bu = WuT + (size_t)e * INTER * HIDDEN;

    __shared__ short As[128 * 32];
    __shared__ short Bgs[128 * 32];
    __shared__ short Bus[128 * 32];

    int tid = threadIdx.x;
    int wave = tid >> 6, lane = tid & 63;
    int wr = wave >> 1, wc = wave & 1;

    // staging geometry: per wave, chunk i (0/1) covers tile rows wave*32+i*16+(lane>>2),
    // bytes (lane&3)*16 within the 64B row; LDS dest = wave*2048 + i*1024 bytes.
    int srow0 = wave * 32 + (lane >> 2);
    int kq = (lane & 3) * 8;  // element offset within row
    int r0 = m0 + srow0, r1 = r0 + 16;
    int rr0 = base + (r0 < mcnt ? r0 : mcnt - 1);
    int rr1 = base + (r1 < mcnt ? r1 : mcnt - 1);
    size_t tokA0 = (size_t)(tok_of_row[rr0] >> 1);
    size_t tokA1 = (size_t)(tok_of_row[rr1] >> 1);

    f32x4 accG[4][4] = {};
    f32x4 accU[4][4] = {};

    for (int k0 = 0; k0 < HIDDEN; k0 += 32) {
        GLDS16(xb + tokA0 * HIDDEN + k0 + kq, &As[wave * 1024]);
        GLDS16(xb + tokA1 * HIDDEN + k0 + kq, &As[wave * 1024 + 512]);
        GLDS16(Bg + (size_t)(n0 + srow0) * HIDDEN + k0 + kq, &Bgs[wave * 1024]);
        GLDS16(Bg + (size_t)(n0 + srow0 + 16) * HIDDEN + k0 + kq, &Bgs[wave * 1024 + 512]);
        GLDS16(Bu + (size_t)(n0 + srow0) * HIDDEN + k0 + kq, &Bus[wave * 1024]);
        GLDS16(Bu + (size_t)(n0 + srow0 + 16) * HIDDEN + k0 + kq, &Bus[wave * 1024 + 512]);
        __syncthreads();
        short8 a[4], bg[4], bu[4];
#pragma unroll
        for (int mi = 0; mi < 4; mi++)
            a[mi] = *reinterpret_cast<const short8*>(
                &As[(wr * 64 + mi * 16 + (lane & 15)) * 32 + (lane >> 4) * 8]);
#pragma unroll
        for (int ni = 0; ni < 4; ni++) {
            bg[ni] = *reinterpret_cast<const short8*>(
                &Bgs[(wc * 64 + ni * 16 + (lane & 15)) * 32 + (lane >> 4) * 8]);
            bu[ni] = *reinterpret_cast<const short8*>(
                &Bus[(wc * 64 + ni * 16 + (lane & 15)) * 32 + (lane >> 4) * 8]);
        }
#pragma unroll
        for (int mi = 0; mi < 4; mi++)
#pragma unroll
            for (int ni = 0; ni < 4; ni++) {
                accG[mi][ni] = __builtin_amdgcn_mfma_f32_16x16x32_bf16(
                    a[mi], bg[ni], accG[mi][ni], 0, 0, 0);
                accU[mi][ni] = __builtin_amdgcn_mfma_f32_16x16x32_bf16(
                    a[mi], bu[ni], accU[mi][ni], 0, 0, 0);
            }
        __syncthreads();
    }

    // epilogue: silu(g)*u -> bf16 act (compact rows)
#pragma unroll
    for (int mi = 0; mi < 4; mi++) {
#pragma unroll
        for (int ni = 0; ni < 4; ni++) {
            int col = n0 + wc * 64 + ni * 16 + (lane & 15);
#pragma unroll
            for (int r = 0; r < 4; r++) {
                int gm = m0 + wr * 64 + mi * 16 + (lane >> 4) * 4 + r;
                if (gm < mcnt) {
                    float g = accG[mi][ni][r], u = accU[mi][ni][r];
                    act[(size_t)(base + gm) * INTER + col] = f2bf(silu_f(g) * u);
                }
            }
        }
    }
}

// ---------------- MFMA grouped GEMM 2: out += w * (act @ Wd) ---------------
// A: act [TROWS][INTER] bf16 compact; B: WdT [panel][HIDDEN][INTER]
__global__ __launch_bounds__(256, 2) void gemm_down(
    const ushort_t* __restrict__ act, const ushort_t* __restrict__ WdT,
    float* __restrict__ out, const int* __restrict__ tok_of_row,
    const float* __restrict__ w_of_row, const int* __restrict__ offs2,
    const int* __restrict__ cnt2) {
    int e = blockIdx.z;
    int mcnt = cnt2[e];
    int m0 = blockIdx.y * 128;
    if (m0 >= mcnt) return;
    int base = offs2[e];
    int n0 = blockIdx.x * 128;
    const ushort_t* Bd = WdT + (size_t)e * HIDDEN * INTER;

    __shared__ short As[128 * 32];
    __shared__ short Bs[128 * 32];

    int tid = threadIdx.x;
    int wave = tid >> 6, lane = tid & 63;
    int wr = wave >> 1, wc = wave & 1;

    int srow0 = wave * 32 + (lane >> 2);
    int kq = (lane & 3) * 8;
    size_t arow0 = (size_t)(base + m0 + srow0);        // stays inside act[TROWS]
    size_t arow1 = arow0 + 16;

    f32x4 acc[4][4] = {};

    for (int k0 = 0; k0 < INTER; k0 += 32) {
        GLDS16(act + arow0 * INTER + k0 + kq, &As[wave * 1024]);
        GLDS16(act + arow1 * INTER + k0 + kq, &As[wave * 1024 + 512]);
        GLDS16(Bd + (size_t)(n0 + srow0) * INTER + k0 + kq, &Bs[wave * 1024]);
        GLDS16(Bd + (size_t)(n0 + srow0 + 16) * INTER + k0 + kq, &Bs[wave * 1024 + 512]);
        __syncthreads();
        short8 a[4], b[4];
#pragma unroll
        for (int mi = 0; mi < 4; mi++)
            a[mi] = *reinterpret_cast<const short8*>(
                &As[(wr * 64 + mi * 16 + (lane & 15)) * 32 + (lane >> 4) * 8]);
#pragma unroll
        for (int ni = 0; ni < 4; ni++)
            b[ni] = *reinterpret_cast<const short8*>(
                &Bs[(wc * 64 + ni * 16 + (lane & 15)) * 32 + (lane >> 4) * 8]);
#pragma unroll
        for (int mi = 0; mi < 4; mi++)
#pragma unroll
            for (int ni = 0; ni < 4; ni++)
                acc[mi][ni] = __builtin_amdgcn_mfma_f32_16x16x32_bf16(
                    a[mi], b[ni], acc[mi][ni], 0, 0, 0);
        __syncthreads();
    }

#pragma unroll
    for (int mi = 0; mi < 4; mi++) {
#pragma unroll
        for (int r = 0; r < 4; r++) {
            int gm = m0 + wr * 64 + mi * 16 + (lane >> 4) * 4 + r;
            if (gm < mcnt) {
                int tok = tok_of_row[base + gm] >> 1;
                float w = w_of_row[base + gm];
#pragma unroll
                for (int ni = 0; ni < 4; ni++) {
                    int col = n0 + wc * 64 + ni * 16 + (lane & 15);
                    atomicAdd(&out[(size_t)tok * HIDDEN + col], w * acc[mi][ni][r]);
                }
            }
        }
    }
}

extern "C" void kernel_launch(void* const* d_in, const int* in_sizes, int n_in,
                              void* d_out, int out_size, void* d_ws, size_t ws_size,
                              hipStream_t stream) {
    const float* x   = (const float*)d_in[0];
    const float* gw  = (const float*)d_in[1];
    const float* wg  = (const float*)d_in[2];
    const float* wu  = (const float*)d_in[3];
    const float* wd  = (const float*)d_in[4];
    const float* swg = (const float*)d_in[5];
    const float* swu = (const float*)d_in[6];
    const float* swd = (const float*)d_in[7];
    float* out = (float*)d_out;

    // ---- workspace layout (bf16 buffers first, 16B-aligned) ----
    const size_t XB   = (size_t)NTOK * HIDDEN;            // 4.19M
    const size_t WPAN = (size_t)NPANEL * INTER * HIDDEN;  // 14.4M per tensor
    const size_t ACT  = (size_t)TROWS * INTER;            // 23.1M
    ushort_t* xb  = (ushort_t*)d_ws;
    ushort_t* wgT = xb + XB;
    ushort_t* wuT = wgT + WPAN;
    ushort_t* wdT = wuT + WPAN;
    ushort_t* act = wdT + WPAN;
    int* ib = (int*)(act + ACT);
    int* top_i      = ib;                 // NROWS
    int* rnk        = ib + NROWS;         // NROWS
    int* cnt        = ib + 2 * NROWS;     // 8
    int* offs2      = ib + 2 * NROWS + 8; // 16
    int* cnt2       = offs2 + 16;         // 16
    int* tok_of_row = cnt2 + 16;          // TROWS
    float* top_w    = (float*)(tok_of_row + TROWS);  // NROWS
    float* w_of_row = top_w + NROWS;                 // TROWS

    // ---- 1. dtype conversions (+ weight transposes to [N][K]) ----
    conv_x<<<(NTOK * HIDDEN) / (256 * 4), 256, 0, stream>>>(x, xb);
    dim3 tb(32, 8);
    // routed gate/up: [1024][1408] -> [1408][1024], 8 experts
    tconv<<<dim3(INTER / 32, HIDDEN / 32, NEXP), tb, 0, stream>>>(
        wg, wgT, HIDDEN, INTER, (long)HIDDEN * INTER, (long)INTER * HIDDEN);
    tconv<<<dim3(INTER / 32, HIDDEN / 32, NEXP), tb, 0, stream>>>(
        wu, wuT, HIDDEN, INTER, (long)HIDDEN * INTER, (long)INTER * HIDDEN);
    // shared gate/up: [1024][2816] -> [2816][1024] == panels 8,9 stacked
    tconv<<<dim3(SINTER / 32, HIDDEN / 32, 1), tb, 0, stream>>>(
        swg, wgT + (size_t)8 * INTER * HIDDEN, HIDDEN, SINTER, 0, 0);
    tconv<<<dim3(SINTER / 32, HIDDEN / 32, 1), tb, 0, stream>>>(
        swu, wuT + (size_t)8 * INTER * HIDDEN, HIDDEN, SINTER, 0, 0);
    // routed down: [1408][1024] -> [1024][1408], 8 experts
    tconv<<<dim3(HIDDEN / 32, INTER / 32, NEXP), tb, 0, stream>>>(
        wd, wdT, INTER, HIDDEN, (long)INTER * HIDDEN, (long)HIDDEN * INTER);
    // shared down: [2][1408][1024] -> 2 panels of [1024][1408]
    tconv<<<dim3(HIDDEN / 32, INTER / 32, 2), tb, 0, stream>>>(
        swd, wdT + (size_t)8 * HIDDEN * INTER, INTER, HIDDEN,
        (long)INTER * HIDDEN, (long)HIDDEN * INTER);

    // ---- 2. gate + routing ----
    gate_kernel<<<NTOK, 64, 0, stream>>>(x, gw, top_i, top_w);
    hipMemsetAsync(cnt, 0, 8 * sizeof(int), stream);
    assign_kernel<<<NROWS / 256, 256, 0, stream>>>(top_i, cnt, rnk);
    scan_kernel<<<1, 1, 0, stream>>>(cnt, offs2, cnt2);
    fill_kernel<<<NROWS / 256, 256, 0, stream>>>(top_i, top_w, rnk, offs2,
                                                 tok_of_row, w_of_row);
    fill_shared<<<NROWS / 256, 256, 0, stream>>>(tok_of_row, w_of_row);

    // ---- 3. grouped SwiGLU GEMMs (routed + shared unified, 10 panels) ----
    gemm_gu<<<dim3(INTER / 128, 64, NPANEL), 256, 0, stream>>>(
        xb, wgT, wuT, act, tok_of_row, offs2, cnt2);
    hipMemsetAsync(out, 0, (size_t)out_size * sizeof(float), stream);
    gemm_down<<<dim3(HIDDEN / 128, 64, NPANEL), 256, 0, stream>>>(
        act, wdT, out, tok_of_row, w_of_row, offs2, cnt2);
}